// Round 1
// baseline (229.529 us; speedup 1.0000x reference)
//
#include <hip/hip_runtime.h>

// SpikingCell recurrence, dead-code-eliminated:
//   clamp gate is always true (clamp starts at 0, only decrements; gate is <=0)
//   sc (spike counter) is never returned
// Per-(b,n) recurrence over t:
//   dvi = (refrac >= 2) ? buf : 0
//   v += dvi; out = (v >= 1); v -= out
//   refrac = out ? 0 : refrac + 1
//   buf = x[b,t,n]
// x layout [B,T,N]; out layout [B,T,N]. Each thread owns one float2 column
// (fixed b, n..n+1), loops over t with stride N. Loads/stores stride-1
// coalesced across the wave; the buf delay makes x[t] loads independent of
// the state chain, so unrolling keeps many loads in flight.

constexpr int B = 16;
constexpr int T = 256;
constexpr int N = 8192;

__global__ __launch_bounds__(256) void spiking_kernel(
    const float* __restrict__ x, float* __restrict__ out) {
  const int c = blockIdx.x * blockDim.x + threadIdx.x;  // 0 .. B*N/2-1
  const int cols = N / 2;                               // float2 columns per batch
  const int b = c / cols;
  const int n2 = c - b * cols;

  const float2* __restrict__ xp =
      reinterpret_cast<const float2*>(x + (size_t)b * T * N) + n2;
  float2* __restrict__ op =
      reinterpret_cast<float2*>(out + (size_t)b * T * N) + n2;

  float2 v = {0.f, 0.f};
  float2 refrac = {0.f, 0.f};
  float2 buf = {0.f, 0.f};

#pragma unroll 8
  for (int t = 0; t < T; ++t) {
    const float2 xt = xp[(size_t)t * cols];
    float2 o;

    float dvi = (refrac.x >= 2.0f) ? buf.x : 0.0f;
    v.x += dvi;
    o.x = (v.x >= 1.0f) ? 1.0f : 0.0f;
    v.x -= o.x;
    refrac.x = (o.x == 0.0f) ? (refrac.x + 1.0f) : 0.0f;
    buf.x = xt.x;

    dvi = (refrac.y >= 2.0f) ? buf.y : 0.0f;
    v.y += dvi;
    o.y = (v.y >= 1.0f) ? 1.0f : 0.0f;
    v.y -= o.y;
    refrac.y = (o.y == 0.0f) ? (refrac.y + 1.0f) : 0.0f;
    buf.y = xt.y;

    op[(size_t)t * cols] = o;
  }
}

extern "C" void kernel_launch(void* const* d_in, const int* in_sizes, int n_in,
                              void* d_out, int out_size, void* d_ws,
                              size_t ws_size, hipStream_t stream) {
  const float* x = (const float*)d_in[0];
  float* out = (float*)d_out;

  const int threads = 256;
  const int total = B * N / 2;  // one thread per float2 column
  const int blocks = total / threads;  // 256 blocks -> 1 block/CU
  spiking_kernel<<<blocks, threads, 0, stream>>>(x, out);
}